// Round 1
// 158.195 us; speedup vs baseline: 1.0652x; 1.0652x over previous
//
#include <hip/hip_runtime.h>

// MetricBiasUpdater: B_next = clip(alpha*B_prev - beta*relu(pairdist(H@W^T)), -10, 10)
// B=4, N=2048, D=1024, K(geom)=32. Output fp32 [4,2048,2048].
//
// v2: k2 rewritten around MFMA. G is stored bf16 (Q computed from the
// ROUNDED values so dist(i,i) cancels before the relu). k2 does the whole
// K=32 gram tile in one mfma_f32_16x16x32_bf16 per 16x16 output tile,
// leaving the kernel purely HBM-streaming (Bp read + out write).

typedef __attribute__((ext_vector_type(8))) short short8;   // 8 bf16 (4 VGPRs)
typedef __attribute__((ext_vector_type(4))) float floatx4;  // MFMA acc

static __device__ __forceinline__ short bf16_bits(float f) {
    union { float f; unsigned int u; } v; v.f = f;
    unsigned int u = v.u;
    u += 0x7FFFu + ((u >> 16) & 1u);   // round-to-nearest-even
    return (short)(u >> 16);
}

static __device__ __forceinline__ float bf16_to_f32(unsigned short h) {
    union { unsigned int u; float f; } v; v.u = ((unsigned int)h) << 16;
    return v.f;
}

// ---------------------------------------------------------------------------
// Kernel 1: G[row][k] = sum_d H[row][d] * W[k][d]  (rows = 8192 flat, k = 32)
// One block = one 16-row m-tile. 4 waves each take a K-quarter (256),
// 8 MFMA steps of K=32, two n-tiles (n=0..15, 16..31). LDS-reduce the 4
// partials, round to bf16, write bf16 G and Q = rowsum(G_bf16^2).
// ---------------------------------------------------------------------------
__global__ __launch_bounds__(256) void k1_proj(const float* __restrict__ H,
                                               const float* __restrict__ W,
                                               unsigned short* __restrict__ G,
                                               float* __restrict__ Q) {
    const int blk  = blockIdx.x;        // 512 blocks x 16 rows
    const int t    = threadIdx.x;
    const int w    = t >> 6;            // wave id -> K quarter
    const int lane = t & 63;
    const int m    = lane & 15;         // A row within tile / B column n
    const int quad = lane >> 4;

    const float* hrow  = H + ((long)blk * 16 + m) * 1024;
    const float* wrow0 = W + (long)m * 1024;          // n-tile 0: n = m
    const float* wrow1 = W + (long)(m + 16) * 1024;   // n-tile 1: n = m+16

    const int kq = w * 256 + quad * 8;  // this lane's k base (A/B frag: k = quad*8 + j)

    floatx4 acc0 = {0.f, 0.f, 0.f, 0.f};
    floatx4 acc1 = {0.f, 0.f, 0.f, 0.f};

    float4 a0  = *(const float4*)(hrow  + kq);
    float4 a1  = *(const float4*)(hrow  + kq + 4);
    float4 b00 = *(const float4*)(wrow0 + kq);
    float4 b01 = *(const float4*)(wrow0 + kq + 4);
    float4 b10 = *(const float4*)(wrow1 + kq);
    float4 b11 = *(const float4*)(wrow1 + kq + 4);

    #pragma unroll
    for (int step = 0; step < 8; ++step) {
        float4 na0, na1, nb00, nb01, nb10, nb11;
        if (step < 7) {                 // prefetch next K-step while MFMA runs
            const int nk = kq + (step + 1) * 32;
            na0  = *(const float4*)(hrow  + nk);
            na1  = *(const float4*)(hrow  + nk + 4);
            nb00 = *(const float4*)(wrow0 + nk);
            nb01 = *(const float4*)(wrow0 + nk + 4);
            nb10 = *(const float4*)(wrow1 + nk);
            nb11 = *(const float4*)(wrow1 + nk + 4);
        }
        short8 af, bf0, bf1;
        af[0] = bf16_bits(a0.x);  af[1] = bf16_bits(a0.y);
        af[2] = bf16_bits(a0.z);  af[3] = bf16_bits(a0.w);
        af[4] = bf16_bits(a1.x);  af[5] = bf16_bits(a1.y);
        af[6] = bf16_bits(a1.z);  af[7] = bf16_bits(a1.w);
        bf0[0] = bf16_bits(b00.x); bf0[1] = bf16_bits(b00.y);
        bf0[2] = bf16_bits(b00.z); bf0[3] = bf16_bits(b00.w);
        bf0[4] = bf16_bits(b01.x); bf0[5] = bf16_bits(b01.y);
        bf0[6] = bf16_bits(b01.z); bf0[7] = bf16_bits(b01.w);
        bf1[0] = bf16_bits(b10.x); bf1[1] = bf16_bits(b10.y);
        bf1[2] = bf16_bits(b10.z); bf1[3] = bf16_bits(b10.w);
        bf1[4] = bf16_bits(b11.x); bf1[5] = bf16_bits(b11.y);
        bf1[6] = bf16_bits(b11.z); bf1[7] = bf16_bits(b11.w);

        acc0 = __builtin_amdgcn_mfma_f32_16x16x32_bf16(af, bf0, acc0, 0, 0, 0);
        acc1 = __builtin_amdgcn_mfma_f32_16x16x32_bf16(af, bf1, acc1, 0, 0, 0);

        if (step < 7) { a0 = na0; a1 = na1; b00 = nb00; b01 = nb01; b10 = nb10; b11 = nb11; }
    }

    // reduce K-quarter partials across the 4 waves.
    // C/D layout: col = lane&15, row = quad*4 + reg  (measured m89)
    __shared__ float red[4][16][32];
    #pragma unroll
    for (int r = 0; r < 4; ++r) {
        red[w][quad * 4 + r][m]      = acc0[r];
        red[w][quad * 4 + r][m + 16] = acc1[r];
    }
    __syncthreads();
    for (int e = t; e < 512; e += 256) {
        const int mm = e >> 5, nn = e & 31;
        float v = red[0][mm][nn] + red[1][mm][nn] + red[2][mm][nn] + red[3][mm][nn];
        const unsigned short hb = (unsigned short)bf16_bits(v);
        G[(long)(blk * 16 + mm) * 32 + nn] = hb;
        red[0][mm][nn] = bf16_to_f32(hb);   // Q from ROUNDED values: dist(i,i) ~ 0
    }
    __syncthreads();
    if (t < 16) {
        float s = 0.f;
        #pragma unroll
        for (int nn = 0; nn < 32; ++nn) { const float v = red[0][t][nn]; s += v * v; }
        Q[blk * 16 + t] = s;
    }
}

// ---------------------------------------------------------------------------
// Kernel 2: out[b][i][j] = clip(alpha*Bp - beta*relu(q[i]+q[j]-2*G[i].G[j]))
// 64(i) x 128(j) tile per block, 4 waves. Each wave owns 16 i-rows:
//   1 A-frag + 8 B-frags + 8x mfma_f32_16x16x32_bf16 (full K=32 in one shot).
// LDS rows padded to 40 shorts (80 B) -> ds_read_b128 is bank-balanced.
// Epilogue: per output row-register, batch 8 Bp loads, then fused
// relu/EMA/clamp and 8 stores. Pure HBM streaming.
// ---------------------------------------------------------------------------
__global__ __launch_bounds__(256) void k2_update(const float* __restrict__ Bp,
                                                 const unsigned short* __restrict__ G,
                                                 const float* __restrict__ Q,
                                                 const float* __restrict__ alphap,
                                                 const float* __restrict__ betap,
                                                 float* __restrict__ out) {
    __shared__ short sGi[64 * 40];    // 64 rows x 32 bf16, stride 40 (80 B)
    __shared__ short sGj[128 * 40];
    __shared__ float sQi[64];
    __shared__ float sQj[128];

    const int b  = blockIdx.z;
    const int i0 = blockIdx.y * 64;
    const int j0 = blockIdx.x * 128;
    const int t  = threadIdx.x;

    const short* Gg = (const short*)G;
    {   // Gi: 64 rows x 4 chunks of 16 B = 256 chunk-loads (1/thread)
        const int r = t >> 2, c = t & 3;
        *(short8*)&sGi[r * 40 + c * 8] =
            *(const short8*)&Gg[(long)(b * 2048 + i0 + r) * 32 + c * 8];
    }
    #pragma unroll
    for (int l = 0; l < 2; ++l) {     // Gj: 128 rows x 4 chunks = 512 (2/thread)
        const int f = t + l * 256;
        const int r = f >> 2, c = f & 3;
        *(short8*)&sGj[r * 40 + c * 8] =
            *(const short8*)&Gg[(long)(b * 2048 + j0 + r) * 32 + c * 8];
    }
    if (t < 64)       sQi[t]      = Q[b * 2048 + i0 + t];
    else if (t < 192) sQj[t - 64] = Q[b * 2048 + j0 + (t - 64)];
    __syncthreads();

    const int w    = t >> 6;          // wave -> i rows [w*16, w*16+16)
    const int lane = t & 63;
    const int m    = lane & 15;
    const int quad = lane >> 4;

    // A/B frag: lane(q,m) holds its source row m, k = quad*8..quad*8+7 (as in k1)
    const short8 af = *(const short8*)&sGi[(w * 16 + m) * 40 + quad * 8];
    floatx4 acc[8];
    #pragma unroll
    for (int jt = 0; jt < 8; ++jt) {
        const short8 bf = *(const short8*)&sGj[(jt * 16 + m) * 40 + quad * 8];
        floatx4 z = {0.f, 0.f, 0.f, 0.f};
        acc[jt] = __builtin_amdgcn_mfma_f32_16x16x32_bf16(af, bf, z, 0, 0, 0);
    }

    const float alpha = alphap[0];
    const float beta  = betap[0];

    float qj[8];
    #pragma unroll
    for (int jt = 0; jt < 8; ++jt) qj[jt] = sQj[jt * 16 + m];

    // D layout: row = quad*4 + r (i), col = m (j) within each 16x16 tile
    const long base = (long)b * 2048 * 2048;
    #pragma unroll
    for (int r = 0; r < 4; ++r) {
        const int i = i0 + w * 16 + quad * 4 + r;
        const float qi = sQi[w * 16 + quad * 4 + r];
        const float* bprow = Bp  + base + (long)i * 2048 + j0 + m;
        float*       orow  = out + base + (long)i * 2048 + j0 + m;
        float bv[8];
        #pragma unroll
        for (int jt = 0; jt < 8; ++jt) bv[jt] = bprow[jt * 16];   // 8 loads in flight
        #pragma unroll
        for (int jt = 0; jt < 8; ++jt) {
            float d = qi + qj[jt] - 2.f * acc[jt][r];
            d = fmaxf(d, 0.f);
            orow[jt * 16] = fminf(fmaxf(alpha * bv[jt] - beta * d, -10.f), 10.f);
        }
    }
}

extern "C" void kernel_launch(void* const* d_in, const int* in_sizes, int n_in,
                              void* d_out, int out_size, void* d_ws, size_t ws_size,
                              hipStream_t stream) {
    const float* H     = (const float*)d_in[0];   // [4,2048,1024]
    const float* Bp    = (const float*)d_in[1];   // [4,2048,2048]
    const float* W     = (const float*)d_in[2];   // [32,1024]
    const float* alpha = (const float*)d_in[3];
    const float* beta  = (const float*)d_in[4];
    float* out = (float*)d_out;

    unsigned short* G = (unsigned short*)d_ws;        // [8192][32] bf16 = 512 KB
    float* Q = (float*)((char*)d_ws + 8192 * 32 * 2); // [8192] fp32 = 32 KB

    k1_proj<<<512, 256, 0, stream>>>(H, W, G, Q);

    dim3 g2(16, 32, 4);               // j-tiles(128), i-tiles(64), batch
    k2_update<<<g2, 256, 0, stream>>>(Bp, G, Q, alpha, beta, out);
}